// Round 4
// baseline (2784.924 us; speedup 1.0000x reference)
//
#include <hip/hip_runtime.h>
#include <hip/hip_bf16.h>
#include <math.h>

#define N_POINTS 524288
#define NLV      16
#define TSZ      524288
#define TMASK    (TSZ - 1)

struct Params { int res[NLV]; int hmask; };

__global__ __launch_bounds__(256, 2)
void nerf_fused(const float* __restrict__ x,
                const float* __restrict__ tables,
                const float* __restrict__ ws0,
                const float* __restrict__ ws1,
                const float* __restrict__ wc0,
                const float* __restrict__ wc1,
                const float* __restrict__ wc2,
                const float* __restrict__ wn0,
                const float* __restrict__ wn1,
                const float* __restrict__ wm0,
                const float* __restrict__ bm0,
                const float* __restrict__ wm1,
                const float* __restrict__ bm1,
                float* __restrict__ out,
                Params P)
{
    const int n = blockIdx.x * 256 + threadIdx.x;
    if (n >= N_POINTS) return;

    // ---- load point: xyz + view dir ----
    const float2* xin = (const float2*)(x + (size_t)n * 6);
    const float2 q0 = xin[0], q1 = xin[1], q2 = xin[2];
    const float dx = q1.y, dy = q2.x, dz = q2.y;
    // fp32 geometry, bit-exact with the fp32 numpy golden (same op order):
    const float xn0 = fminf(fmaxf((q0.x + 1.0f) * 0.5f, 0.0f), 1.0f);
    const float xn1 = fminf(fmaxf((q0.y + 1.0f) * 0.5f, 0.0f), 1.0f);
    const float xn2 = fminf(fmaxf((q1.x + 1.0f) * 0.5f, 0.0f), 1.0f);

    const float2* tb = (const float2*)tables;

    // ---- hashgrid forward: enc[32], NO fused mul-add (match numpy scalar
    //      reduction: round the product, then round the add) ----
    float enc[32];
    {
        #pragma clang fp contract(off)
        #pragma unroll
        for (int l = 0; l < NLV; ++l) {
            const int res = P.res[l];
            const float rf = (float)(res - 1);
            const float px = xn0 * rf, py = xn1 * rf, pz = xn2 * rf;
            const float bx = floorf(px), by = floorf(py), bz = floorf(pz);
            const int ix = (int)bx, iy = (int)by, iz = (int)bz;
            const float fx = px - bx, fy = py - by, fz = pz - bz;
            const bool hashed = (P.hmask >> l) & 1;
            const float2* lt = tb + (size_t)l * TSZ;
            float e0 = 0.0f, e1 = 0.0f;
            #pragma unroll
            for (int c = 0; c < 8; ++c) {
                const int ox = (c >> 2) & 1, oy = (c >> 1) & 1, oz = c & 1;
                int cx = min(max(ix + ox, 0), res - 1);
                int cy = min(max(iy + oy, 0), res - 1);
                int cz = min(max(iz + oz, 0), res - 1);
                const float w = (ox ? fx : 1.0f - fx) * (oy ? fy : 1.0f - fy) * (oz ? fz : 1.0f - fz);
                unsigned idx;
                if (hashed)
                    idx = ((unsigned)cx ^ ((unsigned)cy * 2654435761u) ^ ((unsigned)cz * 805459861u)) & TMASK;
                else
                    idx = (unsigned)(cx + res * (cy + res * cz));
                const float2 t = lt[idx];
                const float p0v = w * t.x;   // rounded product
                e0 = e0 + p0v;               // rounded add
                const float p1v = w * t.y;
                e1 = e1 + p1v;
            }
            enc[2 * l]     = e0;
            enc[2 * l + 1] = e1;
        }
    }

    // ---- density MLP layer 0: pre[64] = enc @ ws0, NO fused mul-add ----
    float pre[64];
    #pragma unroll
    for (int k = 0; k < 64; ++k) pre[k] = 0.0f;
    {
        #pragma clang fp contract(off)
        #pragma unroll
        for (int j = 0; j < 32; ++j) {
            const float ej = enc[j];
            #pragma unroll
            for (int k = 0; k < 64; ++k) {
                const float pv = ej * ws0[j * 64 + k];
                pre[k] = pre[k] + pv;
            }
        }
    }

    // ---- layer 1 fwd (hd = relu(pre) @ ws1) and mask*ws1[:,0] into pre[] ----
    float hd[16];
    #pragma unroll
    for (int m = 0; m < 16; ++m) hd[m] = 0.0f;
    #pragma unroll
    for (int k = 0; k < 64; ++k) {
        const float pk = pre[k];
        const float hr = fmaxf(pk, 0.0f);
        #pragma unroll
        for (int m = 0; m < 16; ++m) hd[m] = fmaf(hr, ws1[k * 16 + m], hd[m]);
        pre[k] = (pk > 0.0f) ? ws1[k * 16] : 0.0f;   // gh[k] for backward
    }
    const float sigma = hd[0];
    float geo[15];
    #pragma unroll
    for (int j = 0; j < 15; ++j) geo[j] = hd[1 + j];

    // ---- genc[32] = ws0 @ gh (linear, value-continuous -> fmaf fine) ----
    float genc[32];
    #pragma unroll
    for (int j = 0; j < 32; ++j) {
        float a = 0.0f;
        #pragma unroll
        for (int k = 0; k < 64; ++k) a = fmaf(ws0[j * 64 + k], pre[k], a);
        genc[j] = a;
    }

    // ---- hashgrid backward: fp32 floors (identical to forward) ----
    float gx = 0.0f, gy = 0.0f, gz = 0.0f;
    #pragma unroll
    for (int l = 0; l < NLV; ++l) {
        const int res = P.res[l];
        const float rf = (float)(res - 1);
        const float px = xn0 * rf, py = xn1 * rf, pz = xn2 * rf;
        const float bx = floorf(px), by = floorf(py), bz = floorf(pz);
        const int ix = (int)bx, iy = (int)by, iz = (int)bz;
        const float fx = px - bx, fy = py - by, fz = pz - bz;
        const bool hashed = (P.hmask >> l) & 1;
        const float2* lt = tb + (size_t)l * TSZ;
        const float g0 = genc[2 * l], g1 = genc[2 * l + 1];
        float lx = 0.0f, ly = 0.0f, lz = 0.0f;
        #pragma unroll
        for (int c = 0; c < 8; ++c) {
            const int ox = (c >> 2) & 1, oy = (c >> 1) & 1, oz = c & 1;
            int cx = min(max(ix + ox, 0), res - 1);
            int cy = min(max(iy + oy, 0), res - 1);
            int cz = min(max(iz + oz, 0), res - 1);
            unsigned idx;
            if (hashed)
                idx = ((unsigned)cx ^ ((unsigned)cy * 2654435761u) ^ ((unsigned)cz * 805459861u)) & TMASK;
            else
                idx = (unsigned)(cx + res * (cy + res * cz));
            const float2 t = lt[idx];
            const float s = fmaf(g0, t.x, g1 * t.y);
            const float wxc = ox ? fx : 1.0f - fx;
            const float wyc = oy ? fy : 1.0f - fy;
            const float wzc = oz ? fz : 1.0f - fz;
            const float sx = ox ? 1.0f : -1.0f;
            const float sy = oy ? 1.0f : -1.0f;
            const float sz = oz ? 1.0f : -1.0f;
            lx = fmaf(sx * (wyc * wzc), s, lx);
            ly = fmaf(sy * (wxc * wzc), s, ly);
            lz = fmaf(sz * (wxc * wyc), s, lz);
        }
        gx = fmaf(lx, rf, gx);
        gy = fmaf(ly, rf, gy);
        gz = fmaf(lz, rf, gz);
    }
    gx *= 0.5f; gy *= 0.5f; gz *= 0.5f;

    // ---- normal = l2_normalize(-grad) ----
    const float gnorm = sqrtf(gx * gx + gy * gy + gz * gz);
    const float ginv = 1.0f / fmaxf(gnorm, 1e-8f);
    const float nx = -gx * ginv, ny = -gy * ginv, nz = -gz * ginv;

    // ---- pred_normal = l2_normalize(relu(geo @ wn0) @ wn1) ----
    float pn0 = 0.0f, pn1 = 0.0f, pn2 = 0.0f;
    #pragma unroll
    for (int k = 0; k < 64; ++k) {
        float a = 0.0f;
        #pragma unroll
        for (int j = 0; j < 15; ++j) a = fmaf(geo[j], wn0[j * 64 + k], a);
        a = fmaxf(a, 0.0f);
        pn0 = fmaf(a, wn1[k * 3 + 0], pn0);
        pn1 = fmaf(a, wn1[k * 3 + 1], pn1);
        pn2 = fmaf(a, wn1[k * 3 + 2], pn2);
    }
    const float pnorm = sqrtf(pn0 * pn0 + pn1 * pn1 + pn2 * pn2);
    const float pinv = 1.0f / fmaxf(pnorm, 1e-8f);

    // ---- spherical harmonics of d ----
    float sh[16];
    const float xy = dx * dy, xz = dx * dz, yz = dy * dz;
    const float x2 = dx * dx, y2 = dy * dy, z2 = dz * dz;
    sh[0]  = 0.28209479177387814f;
    sh[1]  = -0.48860251190291987f * dy;
    sh[2]  =  0.48860251190291987f * dz;
    sh[3]  = -0.48860251190291987f * dx;
    sh[4]  =  1.0925484305920792f * xy;
    sh[5]  = -1.0925484305920792f * yz;
    sh[6]  =  0.94617469575756f * z2 - 0.31539156525252005f;
    sh[7]  = -1.0925484305920792f * xz;
    sh[8]  =  0.5462742152960396f * (x2 - y2);
    sh[9]  =  0.5900435899266435f * dy * (-3.0f * x2 + y2);
    sh[10] =  2.890611442640554f * xy * dz;
    sh[11] =  0.4570457994644657f * dy * (1.0f - 5.0f * z2);
    sh[12] =  0.3731763325901154f * dz * (5.0f * z2 - 3.0f);
    sh[13] =  0.4570457994644657f * dx * (1.0f - 5.0f * z2);
    sh[14] =  1.445305721320277f * dz * (x2 - y2);
    sh[15] =  0.5900435899266435f * dx * (x2 - 3.0f * y2);

    // ---- color MLP: h=[sh, geo] (31) -> 64 -> 64 -> 3, sigmoid ----
    float c1[64];
    #pragma unroll
    for (int k = 0; k < 64; ++k) {
        float a = 0.0f;
        #pragma unroll
        for (int j = 0; j < 16; ++j) a = fmaf(sh[j], wc0[j * 64 + k], a);
        #pragma unroll
        for (int j = 0; j < 15; ++j) a = fmaf(geo[j], wc0[(16 + j) * 64 + k], a);
        c1[k] = fmaxf(a, 0.0f);
    }
    float r0 = 0.0f, r1 = 0.0f, r2 = 0.0f;
    #pragma unroll
    for (int k = 0; k < 64; ++k) {
        float a = 0.0f;
        #pragma unroll
        for (int j = 0; j < 64; ++j) a = fmaf(c1[j], wc1[j * 64 + k], a);
        a = fmaxf(a, 0.0f);
        r0 = fmaf(a, wc2[k * 3 + 0], r0);
        r1 = fmaf(a, wc2[k * 3 + 1], r1);
        r2 = fmaf(a, wc2[k * 3 + 2], r2);
    }
    const float rgb0 = 1.0f / (1.0f + expf(-r0));
    const float rgb1 = 1.0f / (1.0f + expf(-r1));
    const float rgb2 = 1.0f / (1.0f + expf(-r2));

    // ---- mirror head ----
    float macc = 0.0f;
    #pragma unroll
    for (int k = 0; k < 32; ++k) {
        float a = bm0[k];
        #pragma unroll
        for (int j = 0; j < 15; ++j) a = fmaf(geo[j], wm0[j * 32 + k], a);
        a = (a >= 0.0f) ? a : 0.01f * a;
        macc = fmaf(a, wm1[k], macc);
    }
    macc += bm1[0];
    const float mir = 1.0f / (1.0f + expf(-macc));

    // ---- write outputs (concatenated flat, fp32) ----
    const size_t N = (size_t)N_POINTS;
    out[n] = sigma;
    #pragma unroll
    for (int j = 0; j < 15; ++j)
        out[N + (size_t)n * 15 + j] = geo[j];
    out[16 * N + (size_t)n * 3 + 0] = nx;
    out[16 * N + (size_t)n * 3 + 1] = ny;
    out[16 * N + (size_t)n * 3 + 2] = nz;
    out[19 * N + (size_t)n * 3 + 0] = pn0 * pinv;
    out[19 * N + (size_t)n * 3 + 1] = pn1 * pinv;
    out[19 * N + (size_t)n * 3 + 2] = pn2 * pinv;
    out[22 * N + (size_t)n * 3 + 0] = rgb0;
    out[22 * N + (size_t)n * 3 + 1] = rgb1;
    out[22 * N + (size_t)n * 3 + 2] = rgb2;
    out[25 * N + n] = mir;
}

extern "C" void kernel_launch(void* const* d_in, const int* in_sizes, int n_in,
                              void* d_out, int out_size, void* d_ws, size_t ws_size,
                              hipStream_t stream)
{
    // Replicate Python's RES computation bit-for-bit:
    // PLS = exp2(log2(2048.0*BOUND/N_LEVELS)/(N_LEVELS-1)); RES[l] = floor(16*PLS**l)
    Params P;
    const double PLS = exp2(log2(2048.0 * 1.0 / 16.0) / 15.0);
    P.hmask = 0;
    for (int l = 0; l < NLV; ++l) {
        const int r = (int)floor(16.0 * pow(PLS, (double)l));
        P.res[l] = r;
        if ((long long)r * (long long)r * (long long)r > (long long)TSZ)
            P.hmask |= (1 << l);
    }

    nerf_fused<<<N_POINTS / 256, 256, 0, stream>>>(
        (const float*)d_in[0],   // x
        (const float*)d_in[1],   // tables
        (const float*)d_in[2],   // ws0
        (const float*)d_in[3],   // ws1
        (const float*)d_in[4],   // wc0
        (const float*)d_in[5],   // wc1
        (const float*)d_in[6],   // wc2
        (const float*)d_in[7],   // wn0
        (const float*)d_in[8],   // wn1
        (const float*)d_in[9],   // wm0
        (const float*)d_in[10],  // bm0
        (const float*)d_in[11],  // wm1
        (const float*)d_in[12],  // bm1
        (float*)d_out, P);
}

// Round 5
// 2364.758 us; speedup vs baseline: 1.1777x; 1.1777x over previous
//
#include <hip/hip_runtime.h>
#include <hip/hip_bf16.h>
#include <math.h>

#define N_POINTS 524288
#define NLV      16
#define TSZ      524288
#define TMASK    (TSZ - 1)
#define ASTART   5                  // levels >= ASTART: backward via in-register coeffs
#define NA       (NLV - ASTART)     // 11

struct Params { int res[NLV]; int hmask; };

__global__ __launch_bounds__(256, 4)
void nerf_fused(const float* __restrict__ x,
                const float* __restrict__ tables,
                const float* __restrict__ ws0,
                const float* __restrict__ ws1,
                const float* __restrict__ wc0,
                const float* __restrict__ wc1,
                const float* __restrict__ wc2,
                const float* __restrict__ wn0,
                const float* __restrict__ wn1,
                const float* __restrict__ wm0,
                const float* __restrict__ bm0,
                const float* __restrict__ wm1,
                const float* __restrict__ bm1,
                float* __restrict__ out,
                Params P)
{
    const int n = blockIdx.x * 256 + threadIdx.x;
    if (n >= N_POINTS) return;

    // ---- load xyz only (view dir reloaded later to cut register pressure) ----
    const float x0 = x[(size_t)n * 6 + 0];
    const float x1 = x[(size_t)n * 6 + 1];
    const float x2 = x[(size_t)n * 6 + 2];
    const float xn0 = fminf(fmaxf((x0 + 1.0f) * 0.5f, 0.0f), 1.0f);
    const float xn1 = fminf(fmaxf((x1 + 1.0f) * 0.5f, 0.0f), 1.0f);
    const float xn2 = fminf(fmaxf((x2 + 1.0f) * 0.5f, 0.0f), 1.0f);

    const float2* tb = (const float2*)tables;

    // ---- single gather pass: enc[32] (bit-exact order) + backward coeffs A ----
    float enc[32];
    float A0x[NA], A0y[NA], A0z[NA], A1x[NA], A1y[NA], A1z[NA];
    {
        #pragma clang fp contract(off)
        #pragma unroll
        for (int l = 0; l < NLV; ++l) {
            const int res = P.res[l];
            const float rf = (float)(res - 1);
            const float px = xn0 * rf, py = xn1 * rf, pz = xn2 * rf;
            const float bx = floorf(px), by = floorf(py), bz = floorf(pz);
            const int ix = (int)bx, iy = (int)by, iz = (int)bz;
            const float fx = px - bx, fy = py - by, fz = pz - bz;
            const bool hashed = (P.hmask >> l) & 1;
            const float2* lt = tb + (size_t)l * TSZ;
            float e0 = 0.0f, e1 = 0.0f;
            float a0x = 0.0f, a0y = 0.0f, a0z = 0.0f;
            float a1x = 0.0f, a1y = 0.0f, a1z = 0.0f;
            #pragma unroll
            for (int c = 0; c < 8; ++c) {
                const int ox = (c >> 2) & 1, oy = (c >> 1) & 1, oz = c & 1;
                int cx = min(max(ix + ox, 0), res - 1);
                int cy = min(max(iy + oy, 0), res - 1);
                int cz = min(max(iz + oz, 0), res - 1);
                unsigned idx;
                if (hashed)
                    idx = ((unsigned)cx ^ ((unsigned)cy * 2654435761u) ^ ((unsigned)cz * 805459861u)) & TMASK;
                else
                    idx = (unsigned)(cx + res * (cy + res * cz));
                const float2 t = lt[idx];
                const float wx = ox ? fx : 1.0f - fx;
                const float wy = oy ? fy : 1.0f - fy;
                const float wz = oz ? fz : 1.0f - fz;
                const float wxy = wx * wy;           // same rounding order as
                const float w   = wxy * wz;          // ((wx*wy)*wz) in the ref
                const float p0 = w * t.x;            // separate mul ...
                e0 = e0 + p0;                        // ... separate add
                const float p1 = w * t.y;
                e1 = e1 + p1;
                if (l >= ASTART) {                   // value-continuous: fmaf ok
                    const float wyz = wy * wz;
                    const float wxz = wx * wz;
                    const float cyz = ox ? wyz : -wyz;
                    const float cxz = oy ? wxz : -wxz;
                    const float cxy = oz ? wxy : -wxy;
                    a0x = fmaf(cyz, t.x, a0x);  a1x = fmaf(cyz, t.y, a1x);
                    a0y = fmaf(cxz, t.x, a0y);  a1y = fmaf(cxz, t.y, a1y);
                    a0z = fmaf(cxy, t.x, a0z);  a1z = fmaf(cxy, t.y, a1z);
                }
            }
            enc[2 * l]     = e0;
            enc[2 * l + 1] = e1;
            if (l >= ASTART) {
                A0x[l - ASTART] = a0x;  A1x[l - ASTART] = a1x;
                A0y[l - ASTART] = a0y;  A1y[l - ASTART] = a1y;
                A0z[l - ASTART] = a0z;  A1z[l - ASTART] = a1z;
            }
        }
    }

    // ---- density MLP: pre never materialized; relu-sign mask kept in 64 bits.
    //      pre_k accumulated j=0..31 with separate mul/add (bit-exact vs ref). ----
    float hd[16];
    #pragma unroll
    for (int m = 0; m < 16; ++m) hd[m] = 0.0f;
    unsigned long long mask = 0ull;
    {
        #pragma clang fp contract(off)
        #pragma unroll
        for (int k = 0; k < 64; ++k) {
            float a = 0.0f;
            #pragma unroll
            for (int j = 0; j < 32; ++j) {
                const float p = enc[j] * ws0[j * 64 + k];
                a = a + p;
            }
            const float hr = fmaxf(a, 0.0f);
            #pragma unroll
            for (int m = 0; m < 16; ++m) hd[m] = fmaf(hr, ws1[k * 16 + m], hd[m]);
            if (a > 0.0f) mask |= (1ull << k);
        }
    }
    const float sigma = hd[0];

    // ---- genc[32] = ws0 @ (mask .* ws1[:,0]) ----
    float genc[32];
    #pragma unroll
    for (int j = 0; j < 32; ++j) genc[j] = 0.0f;
    #pragma unroll
    for (int k = 0; k < 64; ++k) {
        const float ghk = ((mask >> k) & 1ull) ? ws1[k * 16] : 0.0f;
        #pragma unroll
        for (int j = 0; j < 32; ++j) genc[j] = fmaf(ws0[j * 64 + k], ghk, genc[j]);
    }

    // ---- gradient: dense low levels re-gathered (L2-hot), high levels from A ----
    float gx = 0.0f, gy = 0.0f, gz = 0.0f;
    #pragma unroll
    for (int l = 0; l < ASTART; ++l) {
        const int res = P.res[l];
        const float rf = (float)(res - 1);
        const float px = xn0 * rf, py = xn1 * rf, pz = xn2 * rf;
        const float bx = floorf(px), by = floorf(py), bz = floorf(pz);
        const int ix = (int)bx, iy = (int)by, iz = (int)bz;
        const float fx = px - bx, fy = py - by, fz = pz - bz;
        const bool hashed = (P.hmask >> l) & 1;
        const float2* lt = tb + (size_t)l * TSZ;
        const float g0 = genc[2 * l], g1 = genc[2 * l + 1];
        float lx = 0.0f, ly = 0.0f, lz = 0.0f;
        #pragma unroll
        for (int c = 0; c < 8; ++c) {
            const int ox = (c >> 2) & 1, oy = (c >> 1) & 1, oz = c & 1;
            int cx = min(max(ix + ox, 0), res - 1);
            int cy = min(max(iy + oy, 0), res - 1);
            int cz = min(max(iz + oz, 0), res - 1);
            unsigned idx;
            if (hashed)
                idx = ((unsigned)cx ^ ((unsigned)cy * 2654435761u) ^ ((unsigned)cz * 805459861u)) & TMASK;
            else
                idx = (unsigned)(cx + res * (cy + res * cz));
            const float2 t = lt[idx];
            const float s = fmaf(g0, t.x, g1 * t.y);
            const float wx = ox ? fx : 1.0f - fx;
            const float wy = oy ? fy : 1.0f - fy;
            const float wz = oz ? fz : 1.0f - fz;
            lx = fmaf(ox ? (wy * wz) : -(wy * wz), s, lx);
            ly = fmaf(oy ? (wx * wz) : -(wx * wz), s, ly);
            lz = fmaf(oz ? (wx * wy) : -(wx * wy), s, lz);
        }
        gx = fmaf(lx, rf, gx);
        gy = fmaf(ly, rf, gy);
        gz = fmaf(lz, rf, gz);
    }
    #pragma unroll
    for (int l = ASTART; l < NLV; ++l) {
        const int i = l - ASTART;
        const float rf = (float)(P.res[l] - 1);
        const float g0 = genc[2 * l], g1 = genc[2 * l + 1];
        gx = fmaf(rf, fmaf(g0, A0x[i], g1 * A1x[i]), gx);
        gy = fmaf(rf, fmaf(g0, A0y[i], g1 * A1y[i]), gy);
        gz = fmaf(rf, fmaf(g0, A0z[i], g1 * A1z[i]), gz);
    }
    gx *= 0.5f; gy *= 0.5f; gz *= 0.5f;

    // ---- normal = l2_normalize(-grad) ----
    const float gnorm = sqrtf(gx * gx + gy * gy + gz * gz);
    const float ginv = 1.0f / fmaxf(gnorm, 1e-8f);

    float geo[15];
    #pragma unroll
    for (int j = 0; j < 15; ++j) geo[j] = hd[1 + j];

    // ---- pred_normal = l2_normalize(relu(geo @ wn0) @ wn1) ----
    float pn0 = 0.0f, pn1 = 0.0f, pn2 = 0.0f;
    #pragma unroll
    for (int k = 0; k < 64; ++k) {
        float a = 0.0f;
        #pragma unroll
        for (int j = 0; j < 15; ++j) a = fmaf(geo[j], wn0[j * 64 + k], a);
        a = fmaxf(a, 0.0f);
        pn0 = fmaf(a, wn1[k * 3 + 0], pn0);
        pn1 = fmaf(a, wn1[k * 3 + 1], pn1);
        pn2 = fmaf(a, wn1[k * 3 + 2], pn2);
    }
    const float pnorm = sqrtf(pn0 * pn0 + pn1 * pn1 + pn2 * pn2);
    const float pinv = 1.0f / fmaxf(pnorm, 1e-8f);

    // ---- spherical harmonics of d (reloaded here) ----
    const float dx = x[(size_t)n * 6 + 3];
    const float dy = x[(size_t)n * 6 + 4];
    const float dz = x[(size_t)n * 6 + 5];
    float sh[16];
    const float xy = dx * dy, xz = dx * dz, yz = dy * dz;
    const float x2s = dx * dx, y2s = dy * dy, z2s = dz * dz;
    sh[0]  = 0.28209479177387814f;
    sh[1]  = -0.48860251190291987f * dy;
    sh[2]  =  0.48860251190291987f * dz;
    sh[3]  = -0.48860251190291987f * dx;
    sh[4]  =  1.0925484305920792f * xy;
    sh[5]  = -1.0925484305920792f * yz;
    sh[6]  =  0.94617469575756f * z2s - 0.31539156525252005f;
    sh[7]  = -1.0925484305920792f * xz;
    sh[8]  =  0.5462742152960396f * (x2s - y2s);
    sh[9]  =  0.5900435899266435f * dy * (-3.0f * x2s + y2s);
    sh[10] =  2.890611442640554f * xy * dz;
    sh[11] =  0.4570457994644657f * dy * (1.0f - 5.0f * z2s);
    sh[12] =  0.3731763325901154f * dz * (5.0f * z2s - 3.0f);
    sh[13] =  0.4570457994644657f * dx * (1.0f - 5.0f * z2s);
    sh[14] =  1.445305721320277f * dz * (x2s - y2s);
    sh[15] =  0.5900435899266435f * dx * (x2s - 3.0f * y2s);

    // ---- color MLP: [sh, geo] (31) -> 64 -> 64 -> 3, sigmoid ----
    float c1[64];
    #pragma unroll
    for (int k = 0; k < 64; ++k) {
        float a = 0.0f;
        #pragma unroll
        for (int j = 0; j < 16; ++j) a = fmaf(sh[j], wc0[j * 64 + k], a);
        #pragma unroll
        for (int j = 0; j < 15; ++j) a = fmaf(geo[j], wc0[(16 + j) * 64 + k], a);
        c1[k] = fmaxf(a, 0.0f);
    }
    float r0 = 0.0f, r1 = 0.0f, r2 = 0.0f;
    #pragma unroll
    for (int k = 0; k < 64; ++k) {
        float a = 0.0f;
        #pragma unroll
        for (int j = 0; j < 64; ++j) a = fmaf(c1[j], wc1[j * 64 + k], a);
        a = fmaxf(a, 0.0f);
        r0 = fmaf(a, wc2[k * 3 + 0], r0);
        r1 = fmaf(a, wc2[k * 3 + 1], r1);
        r2 = fmaf(a, wc2[k * 3 + 2], r2);
    }
    const float rgb0 = 1.0f / (1.0f + expf(-r0));
    const float rgb1 = 1.0f / (1.0f + expf(-r1));
    const float rgb2 = 1.0f / (1.0f + expf(-r2));

    // ---- mirror head ----
    float macc = 0.0f;
    #pragma unroll
    for (int k = 0; k < 32; ++k) {
        float a = bm0[k];
        #pragma unroll
        for (int j = 0; j < 15; ++j) a = fmaf(geo[j], wm0[j * 32 + k], a);
        a = (a >= 0.0f) ? a : 0.01f * a;
        macc = fmaf(a, wm1[k], macc);
    }
    macc += bm1[0];
    const float mir = 1.0f / (1.0f + expf(-macc));

    // ---- write outputs (concatenated flat, fp32) ----
    const size_t N = (size_t)N_POINTS;
    out[n] = sigma;
    #pragma unroll
    for (int j = 0; j < 15; ++j)
        out[N + (size_t)n * 15 + j] = geo[j];
    out[16 * N + (size_t)n * 3 + 0] = -gx * ginv;
    out[16 * N + (size_t)n * 3 + 1] = -gy * ginv;
    out[16 * N + (size_t)n * 3 + 2] = -gz * ginv;
    out[19 * N + (size_t)n * 3 + 0] = pn0 * pinv;
    out[19 * N + (size_t)n * 3 + 1] = pn1 * pinv;
    out[19 * N + (size_t)n * 3 + 2] = pn2 * pinv;
    out[22 * N + (size_t)n * 3 + 0] = rgb0;
    out[22 * N + (size_t)n * 3 + 1] = rgb1;
    out[22 * N + (size_t)n * 3 + 2] = rgb2;
    out[25 * N + n] = mir;
}

extern "C" void kernel_launch(void* const* d_in, const int* in_sizes, int n_in,
                              void* d_out, int out_size, void* d_ws, size_t ws_size,
                              hipStream_t stream)
{
    // Replicate Python's RES computation bit-for-bit:
    // PLS = exp2(log2(2048.0*BOUND/N_LEVELS)/(N_LEVELS-1)); RES[l] = floor(16*PLS**l)
    Params P;
    const double PLS = exp2(log2(2048.0 * 1.0 / 16.0) / 15.0);
    P.hmask = 0;
    for (int l = 0; l < NLV; ++l) {
        const int r = (int)floor(16.0 * pow(PLS, (double)l));
        P.res[l] = r;
        if ((long long)r * (long long)r * (long long)r > (long long)TSZ)
            P.hmask |= (1 << l);
    }

    nerf_fused<<<N_POINTS / 256, 256, 0, stream>>>(
        (const float*)d_in[0],   // x
        (const float*)d_in[1],   // tables
        (const float*)d_in[2],   // ws0
        (const float*)d_in[3],   // ws1
        (const float*)d_in[4],   // wc0
        (const float*)d_in[5],   // wc1
        (const float*)d_in[6],   // wc2
        (const float*)d_in[7],   // wn0
        (const float*)d_in[8],   // wn1
        (const float*)d_in[9],   // wm0
        (const float*)d_in[10],  // bm0
        (const float*)d_in[11],  // wm1
        (const float*)d_in[12],  // bm1
        (float*)d_out, P);
}